// Round 3
// baseline (297.518 us; speedup 1.0000x reference)
//
#include <hip/hip_runtime.h>
#include <stdint.h>

// DCNv2 fused forward (B=8, C=256, H=W=64, OC=256, 3x3, pad=1, stride=1, DG=1)
// f32-grade accuracy via bf16 hi/lo split GEMM: W*B ~= WhiBhi + WloBhi + WhiBlo.
// bf16 split (not f16): bf16 has f32's exponent range -> lo terms (~2^-9 * |v|)
// never hit subnormal flush.
// Structure = round-1-proven: tile 256 oc x 64 pos (one output row), grid 512,
// 4 waves, 4x4 acc of mfma_f32_16x16x32_bf16, x staged NHWC (now f32).
// LDS row stride 40 ush (80B = 20 banks; 16B-aligned b128; residue-balanced).

typedef __attribute__((ext_vector_type(8))) short bf16x8;
typedef __attribute__((ext_vector_type(4))) float floatx4;
typedef __attribute__((ext_vector_type(4))) unsigned int uintx4;

#define MFMA16(A, B, C) __builtin_amdgcn_mfma_f32_16x16x32_bf16(A, B, C, 0, 0, 0)

__device__ __forceinline__ float bf2f(unsigned int u) {
    union { unsigned int i; float f; } v; v.i = u << 16; return v.f;
}
__device__ __forceinline__ unsigned int f2bf_rne(float f) {
    union { float f; unsigned int i; } v; v.f = f;
    unsigned int u = v.i;
    u += 0x7fffu + ((u >> 16) & 1u);
    return u >> 16;
}
// v ~= bf16(h) + bf16(l), error ~2^-17 relative
__device__ __forceinline__ void split_bf(float v, unsigned int& h, unsigned int& l) {
    h = f2bf_rne(v);
    float hf = bf2f(h);
    l = f2bf_rne(v - hf);
}

// x (8,256,64,64) f32 -> xtf (8,64,64,256) f32  (direct copy, proven indexing;
// reads scattered but single-pass and L3-resident)
__global__ __launch_bounds__(256) void k_prep_x(const float* __restrict__ x,
                                                float* __restrict__ xtf) {
    int tid = blockIdx.x * 256 + threadIdx.x;  // 8*4096*256
    int c = tid & 255;
    int pix = tid >> 8;         // b*4096 + yx
    int b = pix >> 12;
    int yx = pix & 4095;
    xtf[tid] = x[((size_t)(b * 256 + c) << 12) + yx];
}

// weight (256,256,3,3) f32 -> bwH/bwL [step=72][oc=256][kj=32] bf16,
// kk = step*32+kj = ktap*256 + c
__global__ __launch_bounds__(256) void k_prep_w(const float* __restrict__ w,
                                                unsigned short* __restrict__ bwH,
                                                unsigned short* __restrict__ bwL) {
    int tid = blockIdx.x * 256 + threadIdx.x;  // 72*256*32 = 589824
    int kj = tid & 31;
    int oc = (tid >> 5) & 255;
    int step = tid >> 13;
    int ktap = step >> 3;
    int c = ((step & 7) << 5) + kj;
    float v = w[oc * 2304 + c * 9 + ktap];
    unsigned int h, l;
    split_bf(v, h, l);
    bwH[tid] = (unsigned short)h;
    bwL[tid] = (unsigned short)l;
}

template <bool USE_WS>
__global__ __launch_bounds__(256, 2) void k_dcn(
    const float* __restrict__ x,       // fallback only (NCHW f32)
    const float* __restrict__ offset,  // (8,18,64,64)
    const float* __restrict__ mask,    // (8,9,64,64)
    const float* __restrict__ weight,  // fallback only
    const float* __restrict__ bias,    // (256,)
    const float* __restrict__ xtf,     // (8,64,64,256) f32
    const unsigned short* __restrict__ bwH,  // (72,256,32) bf16 hi
    const unsigned short* __restrict__ bwL,  // (72,256,32) bf16 lo
    float* __restrict__ out)           // (8,256,64,64)
{
    __shared__ __align__(16) unsigned short AsH[256 * 40];  // 20480 B
    __shared__ __align__(16) unsigned short AsL[256 * 40];  // 20480 B
    __shared__ __align__(16) unsigned short BsH[64 * 40];   //  5120 B
    __shared__ __align__(16) unsigned short BsL[64 * 40];   //  5120 B
    __shared__ int   cY[64][4];
    __shared__ float cW[64][4];
    // total 55296 B < 64 KiB static limit

    const int t = threadIdx.x;
    const int tile = blockIdx.x;   // 512
    const int b = tile >> 6;
    const int ho = tile & 63;

    const int lane = t & 63;
    const int wid = t >> 6;        // 0..3
    const int quad = lane >> 4;
    const int l15 = lane & 15;

    const int gpos = t >> 2;       // 0..63
    const int gseg = t & 3;

    floatx4 acc[4][4];
#pragma unroll
    for (int i = 0; i < 4; i++)
#pragma unroll
        for (int j = 0; j < 4; j++) acc[i][j] = (floatx4){0.f, 0.f, 0.f, 0.f};

    for (int ktap = 0; ktap < 9; ++ktap) {
        __syncthreads();
        if (t < 64) {
            int wo = t;
            int spos = (ho << 6) + wo;
            float offy = offset[(((size_t)(b * 18 + 2 * ktap)) << 12) + spos];
            float offx = offset[(((size_t)(b * 18 + 2 * ktap + 1)) << 12) + spos];
            float m = mask[(((size_t)(b * 9 + ktap)) << 12) + spos];
            float py = (float)(ktap / 3) + (float)(ho - 1) + offy;
            float px = (float)(ktap % 3) + (float)(wo - 1) + offx;
            float y0f = floorf(py), x0f = floorf(px);
            float wy1 = py - y0f, wx1 = px - x0f;
            float wy0 = 1.f - wy1, wx0 = 1.f - wx1;
            int y0 = (int)y0f, x0 = (int)x0f;
            int y1 = y0 + 1, x1 = x0 + 1;
            bool vy0 = (y0 >= 0) && (y0 < 64), vy1 = (y1 >= 0) && (y1 < 64);
            bool vx0 = (x0 >= 0) && (x0 < 64), vx1 = (x1 >= 0) && (x1 < 64);
            int cy0 = min(max(y0, 0), 63), cy1 = min(max(y1, 0), 63);
            int cx0 = min(max(x0, 0), 63), cx1 = min(max(x1, 0), 63);
            cY[t][0] = cy0 * 64 + cx0;
            cY[t][1] = cy0 * 64 + cx1;
            cY[t][2] = cy1 * 64 + cx0;
            cY[t][3] = cy1 * 64 + cx1;
            cW[t][0] = wy0 * wx0 * m * ((vy0 && vx0) ? 1.f : 0.f);
            cW[t][1] = wy0 * wx1 * m * ((vy0 && vx1) ? 1.f : 0.f);
            cW[t][2] = wy1 * wx0 * m * ((vy1 && vx0) ? 1.f : 0.f);
            cW[t][3] = wy1 * wx1 * m * ((vy1 && vx1) ? 1.f : 0.f);
        }
        __syncthreads();
        const int yx00 = cY[gpos][0], yx01 = cY[gpos][1];
        const int yx10 = cY[gpos][2], yx11 = cY[gpos][3];
        const float w00 = cW[gpos][0], w01 = cW[gpos][1];
        const float w10 = cW[gpos][2], w11 = cW[gpos][3];

        for (int cs = 0; cs < 8; ++cs) {
            const int step = (ktap << 3) + cs;
            const int c0 = cs << 5;

            // ---- stage A hi/lo (256 oc x 32 k): thread t = row t, both arrays ----
            if (USE_WS) {
                const uintx4* sH = (const uintx4*)(bwH + (((size_t)step << 8) + t) * 32);
                const uintx4* sL = (const uintx4*)(bwL + (((size_t)step << 8) + t) * 32);
                uintx4 h0 = sH[0], h1 = sH[1], h2 = sH[2], h3 = sH[3];
                uintx4 l0 = sL[0], l1 = sL[1], l2 = sL[2], l3 = sL[3];
                uintx4* dH = (uintx4*)&AsH[t * 40];
                uintx4* dL = (uintx4*)&AsL[t * 40];
                dH[0] = h0; dH[1] = h1; dH[2] = h2; dH[3] = h3;
                dL[0] = l0; dL[1] = l1; dL[2] = l2; dL[3] = l3;
            } else {
                const float* wp = weight + (size_t)t * 2304 + (size_t)c0 * 9 + ktap;
#pragma unroll
                for (int kj = 0; kj < 32; kj += 2) {
                    unsigned int h0, l0u, h1, l1u;
                    split_bf(wp[kj * 9], h0, l0u);
                    split_bf(wp[kj * 9 + 9], h1, l1u);
                    *(unsigned int*)&AsH[t * 40 + kj] = h0 | (h1 << 16);
                    *(unsigned int*)&AsL[t * 40 + kj] = l0u | (l1u << 16);
                }
            }

            // ---- generate B (64 pos x 32 c): f32 bilinear -> bf16 hi/lo ----
            {
                const int cb = c0 + (gseg << 3);
                float vals[8];
                if (USE_WS) {
                    const float* xb = xtf + ((size_t)b << 20);
                    const floatx4* p00 = (const floatx4*)(xb + ((size_t)yx00 << 8) + cb);
                    const floatx4* p01 = (const floatx4*)(xb + ((size_t)yx01 << 8) + cb);
                    const floatx4* p10 = (const floatx4*)(xb + ((size_t)yx10 << 8) + cb);
                    const floatx4* p11 = (const floatx4*)(xb + ((size_t)yx11 << 8) + cb);
                    floatx4 a0 = p00[0], a1 = p00[1];
                    floatx4 b0 = p01[0], b1 = p01[1];
                    floatx4 g0 = p10[0], g1 = p10[1];
                    floatx4 d0 = p11[0], d1 = p11[1];
#pragma unroll
                    for (int p = 0; p < 4; p++) {
                        vals[p]     = w00 * a0[p] + w01 * b0[p] + w10 * g0[p] + w11 * d0[p];
                        vals[4 + p] = w00 * a1[p] + w01 * b1[p] + w10 * g1[p] + w11 * d1[p];
                    }
                } else {
                    const float* xb = x + ((size_t)b << 20);
#pragma unroll
                    for (int j = 0; j < 8; j++) {
                        const float* xc = xb + ((size_t)(cb + j) << 12);
                        vals[j] = w00 * xc[yx00] + w01 * xc[yx01] +
                                  w10 * xc[yx10] + w11 * xc[yx11];
                    }
                }
                uintx4 pkH, pkL;
#pragma unroll
                for (int p = 0; p < 4; p++) {
                    unsigned int h0, l0u, h1, l1u;
                    split_bf(vals[2 * p], h0, l0u);
                    split_bf(vals[2 * p + 1], h1, l1u);
                    pkH[p] = h0 | (h1 << 16);
                    pkL[p] = l0u | (l1u << 16);
                }
                *(uintx4*)&BsH[gpos * 40 + (gseg << 3)] = pkH;
                *(uintx4*)&BsL[gpos * 40 + (gseg << 3)] = pkL;
            }

            __syncthreads();

            // ---- fragments + 3-product MFMA ----
            bf16x8 aH[4], aL[4], bH[4], bL[4];
#pragma unroll
            for (int i = 0; i < 4; i++) {
                const int rowA = (wid << 6) + (i << 4) + l15;
                aH[i] = *(const bf16x8*)&AsH[rowA * 40 + (quad << 3)];
                aL[i] = *(const bf16x8*)&AsL[rowA * 40 + (quad << 3)];
            }
#pragma unroll
            for (int j = 0; j < 4; j++) {
                const int rowB = (j << 4) + l15;
                bH[j] = *(const bf16x8*)&BsH[rowB * 40 + (quad << 3)];
                bL[j] = *(const bf16x8*)&BsL[rowB * 40 + (quad << 3)];
            }
#pragma unroll
            for (int i = 0; i < 4; i++)
#pragma unroll
                for (int j = 0; j < 4; j++) {
                    acc[i][j] = MFMA16(aH[i], bH[j], acc[i][j]);
                    acc[i][j] = MFMA16(aL[i], bH[j], acc[i][j]);
                    acc[i][j] = MFMA16(aH[i], bL[j], acc[i][j]);
                }

            __syncthreads();
        }
    }

    // ---- epilogue: C/D col=lane&15 -> pos, row=quad*4+r -> oc (R1-proven) ----
    float* outb = out + ((size_t)b << 20);
    const int posbase = ho << 6;
#pragma unroll
    for (int i = 0; i < 4; i++) {
        const int ocb = (wid << 6) + (i << 4) + (quad << 2);
#pragma unroll
        for (int r = 0; r < 4; r++) {
            const float bv = bias[ocb + r];
#pragma unroll
            for (int j = 0; j < 4; j++) {
                const int pos = posbase + (j << 4) + l15;
                outb[((size_t)(ocb + r) << 12) + pos] = acc[i][j][r] + bv;
            }
        }
    }
}

extern "C" void kernel_launch(void* const* d_in, const int* in_sizes, int n_in,
                              void* d_out, int out_size, void* d_ws, size_t ws_size,
                              hipStream_t stream) {
    const float* x      = (const float*)d_in[0];
    const float* offset = (const float*)d_in[1];
    const float* mask   = (const float*)d_in[2];
    const float* weight = (const float*)d_in[3];
    const float* bias   = (const float*)d_in[4];
    float* out = (float*)d_out;

    const size_t xtf_elems = (size_t)8 * 4096 * 256;       // f32 NHWC, 32 MB
    const size_t bw_elems  = (size_t)72 * 256 * 32;        // per hi/lo, bf16
    const size_t need = xtf_elems * 4 + 2 * bw_elems * 2;  // ~34.5 MB

    if (ws_size >= need) {
        float* xtf = (float*)d_ws;
        unsigned short* bwH = (unsigned short*)((char*)d_ws + xtf_elems * 4);
        unsigned short* bwL = bwH + bw_elems;
        k_prep_x<<<(int)(xtf_elems / 256), 256, 0, stream>>>(x, xtf);
        k_prep_w<<<(int)(bw_elems / 256), 256, 0, stream>>>(weight, bwH, bwL);
        k_dcn<true><<<512, 256, 0, stream>>>(x, offset, mask, weight, bias,
                                             xtf, bwH, bwL, out);
    } else {
        k_dcn<false><<<512, 256, 0, stream>>>(x, offset, mask, weight, bias,
                                              nullptr, nullptr, nullptr, out);
    }
}